// Round 3
// baseline (332.684 us; speedup 1.0000x reference)
//
#include <hip/hip_runtime.h>

#define DIM   1024
#define HID   512
#define NEXP  16
#define TOPK  4
#define SLOTS 5
#define BM    64
#define PITCH 72   // 64 + 8 bf16 pad: keeps ds_read_b128 off 4-way+ bank conflicts
#define MAXTILES 176

typedef unsigned short u16;
typedef unsigned int   u32;
typedef short bf16x8 __attribute__((ext_vector_type(8)));
typedef float f32x4  __attribute__((ext_vector_type(4)));

__device__ __forceinline__ u16 f2bf(float f) {
    union { float f; u32 i; } v; v.f = f;
    u32 lsb = (v.i >> 16) & 1u;
    v.i += 0x7fffu + lsb;              // round-to-nearest-even
    return (u16)(v.i >> 16);
}
// pack 8 fp32 -> 8 bf16 in a uint4 (for one ds_write_b128)
__device__ __forceinline__ uint4 pack8(float4 a, float4 b) {
    uint4 r;
    r.x = (u32)f2bf(a.x) | ((u32)f2bf(a.y) << 16);
    r.y = (u32)f2bf(a.z) | ((u32)f2bf(a.w) << 16);
    r.z = (u32)f2bf(b.x) | ((u32)f2bf(b.y) << 16);
    r.w = (u32)f2bf(b.z) | ((u32)f2bf(b.w) << 16);
    return r;
}

// ---------------------------------------------------------------- router ----
// 1 wave per token: 16 logits via butterfly reduce -> top4 (strict >, ties to
// lowest index = lax.top_k) -> softmax over selected 4 (== renormalized topk).
__global__ __launch_bounds__(64) void moe_router(
    const float* __restrict__ x, const float* __restrict__ gate,
    int* __restrict__ counts, u32* __restrict__ pairs,
    float* __restrict__ wslot, int T)
{
    const int t = blockIdx.x;
    const int lane = threadIdx.x;
    const float* xrow = x + (size_t)t * DIM;
    float xr[16];
#pragma unroll
    for (int j = 0; j < 16; ++j) xr[j] = xrow[lane + 64 * j];

    float logit[NEXP];
#pragma unroll
    for (int e = 0; e < NEXP; ++e) {
        const float* g = gate + (size_t)e * DIM;
        float s = 0.f;
#pragma unroll
        for (int j = 0; j < 16; ++j) s += xr[j] * g[lane + 64 * j];
#pragma unroll
        for (int off = 32; off > 0; off >>= 1) s += __shfl_xor(s, off);
        logit[e] = s;   // butterfly: identical across all 64 lanes
    }

    float v[NEXP];
#pragma unroll
    for (int e = 0; e < NEXP; ++e) v[e] = logit[e];
    int idx[TOPK]; float lv[TOPK];
#pragma unroll
    for (int r = 0; r < TOPK; ++r) {
        int be = 0; float bv = v[0];
        for (int e = 1; e < NEXP; ++e) { if (v[e] > bv) { bv = v[e]; be = e; } }
        idx[r] = be; lv[r] = bv; v[be] = -3.0e38f;
    }
    float wk[TOPK]; float wsum = 0.f;
#pragma unroll
    for (int r = 0; r < TOPK; ++r) { wk[r] = __expf(lv[r] - lv[0]); wsum += wk[r]; }
#pragma unroll
    for (int r = 0; r < TOPK; ++r) wk[r] /= wsum;

    if (lane < TOPK) {
        int e = idx[lane];
        int slot = atomicAdd(&counts[e], 1);
        if (slot < T) pairs[(size_t)e * T + slot] = ((u32)t << 3) | (u32)lane;
        wslot[t * SLOTS + lane] = wk[lane];
    } else if (lane == TOPK) {
        pairs[(size_t)NEXP * T + t] = ((u32)t << 3) | 4u;   // shared expert
        wslot[t * SLOTS + 4] = 1.0f;
    }
}

// ---------------------------------------------------------- tile builder ----
__global__ void moe_build_tiles(const int* __restrict__ counts,
    int* __restrict__ tileE, int* __restrict__ tileR0, int* __restrict__ tileNV,
    int* __restrict__ tot, int T)
{
    if (threadIdx.x != 0 || blockIdx.x != 0) return;
    int n = 0;
    for (int e = 0; e <= NEXP; ++e) {
        int c = (e == NEXP) ? T : counts[e];
        c = min(max(c, 0), T);                 // clamp vs corruption
        for (int r = 0; r < c && n < MAXTILES; r += BM) {
            tileE[n] = e; tileR0[n] = r;
            tileNV[n] = min(BM, c - r);
            ++n;
        }
    }
    *tot = n;
}

// ------------------------------------------------------------------ gemm1 ---
// act[t*5+slot][0:512] = silu(x_t . W1_e^T) * (x_t . W3_e^T), grouped (bf16 out).
__global__ __launch_bounds__(256) void moe_gemm1(
    const float* __restrict__ x,
    const float* __restrict__ w1, const float* __restrict__ w3,
    const float* __restrict__ sw1, const float* __restrict__ sw3,
    const u32* __restrict__ pairs,
    const int* __restrict__ tileE, const int* __restrict__ tileR0,
    const int* __restrict__ tileNV, const int* __restrict__ tot,
    u16* __restrict__ act, int T)
{
    const int tile = blockIdx.y;
    if (tile >= min(*tot, MAXTILES)) return;
    const int e  = min(max(tileE[tile], 0), NEXP);          // clamped decodes
    const int r0 = min(max(tileR0[tile], 0), T - 1);
    const int nv = min(max(tileNV[tile], 0), min(BM, T - r0));
    const int n0 = blockIdx.x * 64;

    const float* W1 = (e < NEXP) ? (w1 + (size_t)e * HID * DIM) : sw1;
    const float* W3 = (e < NEXP) ? (w3 + (size_t)e * HID * DIM) : sw3;

    __shared__ __align__(16) u16 sA [64 * PITCH];
    __shared__ __align__(16) u16 sB1[64 * PITCH];
    __shared__ __align__(16) u16 sB3[64 * PITCH];
    __shared__ u32 sEnt[64];

    const int tid = threadIdx.x;
    if (tid < 64) {
        u32 ent = (tid < nv) ? pairs[(size_t)e * T + r0 + tid] : 0u;
        u32 tk = ent >> 3, sl = ent & 7u;                   // clamped decode
        if (tk >= (u32)T) tk = 0;
        if (sl >= SLOTS)  sl = 0;
        sEnt[tid] = (tk << 3) | sl;
    }
    __syncthreads();

    const int lr = tid >> 2;            // staging row 0..63
    const int c0 = (tid & 3) * 16;      // 16 fp32 elems per thread per matrix
    const u32 entA = sEnt[lr];
    const float* xrow  = x  + (size_t)(entA >> 3) * DIM;
    const float* b1row = W1 + (size_t)(n0 + lr) * DIM;
    const float* b3row = W3 + (size_t)(n0 + lr) * DIM;

    const int wv   = tid >> 6;          // wave 0..3 -> M rows [wv*16, +16)
    const int lane = tid & 63;
    const int l15  = lane & 15;
    const int kq   = (lane >> 4) * 8;   // A/B frag: k = quad*8 + j

    f32x4 acc1[4], acc3[4];
#pragma unroll
    for (int i = 0; i < 4; ++i) { acc1[i] = (f32x4){0,0,0,0}; acc3[i] = (f32x4){0,0,0,0}; }

    for (int kt = 0; kt < DIM; kt += 64) {
        __syncthreads();
        {
            float4 a0 = *(const float4*)&xrow [kt + c0];
            float4 a1 = *(const float4*)&xrow [kt + c0 + 4];
            float4 a2 = *(const float4*)&xrow [kt + c0 + 8];
            float4 a3 = *(const float4*)&xrow [kt + c0 + 12];
            *(uint4*)&sA [lr*PITCH + c0]     = pack8(a0, a1);
            *(uint4*)&sA [lr*PITCH + c0 + 8] = pack8(a2, a3);
            float4 b0 = *(const float4*)&b1row[kt + c0];
            float4 b1 = *(const float4*)&b1row[kt + c0 + 4];
            float4 b2 = *(const float4*)&b1row[kt + c0 + 8];
            float4 b3 = *(const float4*)&b1row[kt + c0 + 12];
            *(uint4*)&sB1[lr*PITCH + c0]     = pack8(b0, b1);
            *(uint4*)&sB1[lr*PITCH + c0 + 8] = pack8(b2, b3);
            float4 d0 = *(const float4*)&b3row[kt + c0];
            float4 d1 = *(const float4*)&b3row[kt + c0 + 4];
            float4 d2 = *(const float4*)&b3row[kt + c0 + 8];
            float4 d3 = *(const float4*)&b3row[kt + c0 + 12];
            *(uint4*)&sB3[lr*PITCH + c0]     = pack8(d0, d1);
            *(uint4*)&sB3[lr*PITCH + c0 + 8] = pack8(d2, d3);
        }
        __syncthreads();
#pragma unroll
        for (int ks = 0; ks < 64; ks += 32) {
            bf16x8 af = *(const bf16x8*)&sA[(wv*16 + l15)*PITCH + ks + kq];
#pragma unroll
            for (int nt = 0; nt < 4; ++nt) {
                bf16x8 b1 = *(const bf16x8*)&sB1[(nt*16 + l15)*PITCH + ks + kq];
                bf16x8 b3 = *(const bf16x8*)&sB3[(nt*16 + l15)*PITCH + ks + kq];
                acc1[nt] = __builtin_amdgcn_mfma_f32_16x16x32_bf16(af, b1, acc1[nt], 0, 0, 0);
                acc3[nt] = __builtin_amdgcn_mfma_f32_16x16x32_bf16(af, b3, acc3[nt], 0, 0, 0);
            }
        }
    }
    // C/D layout (m89-verified): col = lane&15, row = (lane>>4)*4 + reg
#pragma unroll
    for (int nt = 0; nt < 4; ++nt) {
#pragma unroll
        for (int r = 0; r < 4; ++r) {
            int ml = wv*16 + (lane >> 4)*4 + r;
            if (ml < nv) {
                float h1 = acc1[nt][r], h3 = acc3[nt][r];
                float a = (h1 / (1.f + __expf(-h1))) * h3;   // silu(h1)*h3
                u32 ent = sEnt[ml];
                size_t sidx = (size_t)(ent >> 3) * SLOTS + (ent & 7u);
                act[sidx * HID + n0 + nt*16 + l15] = f2bf(a);
            }
        }
    }
}

// ------------------------------------------------------------------ gemm2 ---
// out[t][:] += wslot[t][slot] * (act[t*5+slot] . W2_e^T)   (fp32 atomics)
__global__ __launch_bounds__(256) void moe_gemm2(
    const u16* __restrict__ act,
    const float* __restrict__ w2, const float* __restrict__ sw2,
    const u32* __restrict__ pairs, const float* __restrict__ wslot,
    const int* __restrict__ tileE, const int* __restrict__ tileR0,
    const int* __restrict__ tileNV, const int* __restrict__ tot,
    float* __restrict__ out, int T)
{
    const int tile = blockIdx.y;
    if (tile >= min(*tot, MAXTILES)) return;
    const int e  = min(max(tileE[tile], 0), NEXP);
    const int r0 = min(max(tileR0[tile], 0), T - 1);
    const int nv = min(max(tileNV[tile], 0), min(BM, T - r0));
    const int n0 = blockIdx.x * 64;

    const float* W2 = (e < NEXP) ? (w2 + (size_t)e * DIM * HID) : sw2;

    __shared__ __align__(16) u16 sA[64 * PITCH];
    __shared__ __align__(16) u16 sB[64 * PITCH];
    __shared__ u32 sEnt[64];

    const int tid = threadIdx.x;
    if (tid < 64) {
        u32 ent = (tid < nv) ? pairs[(size_t)e * T + r0 + tid] : 0u;
        u32 tk = ent >> 3, sl = ent & 7u;
        if (tk >= (u32)T) tk = 0;
        if (sl >= SLOTS)  sl = 0;
        sEnt[tid] = (tk << 3) | sl;
    }
    __syncthreads();

    const int lr = tid >> 2;
    const int c0 = (tid & 3) * 16;
    const u32 entA = sEnt[lr];
    const u16*   arow = act + ((size_t)(entA >> 3) * SLOTS + (entA & 7u)) * HID;
    const float* brow = W2 + (size_t)(n0 + lr) * HID;

    const int wv   = tid >> 6;
    const int lane = tid & 63;
    const int l15  = lane & 15;
    const int kq   = (lane >> 4) * 8;

    f32x4 acc[4];
#pragma unroll
    for (int i = 0; i < 4; ++i) acc[i] = (f32x4){0,0,0,0};

    for (int kt = 0; kt < HID; kt += 64) {
        __syncthreads();
        {
            // A is already bf16: straight 16B copies (two per thread)
            *(uint4*)&sA[lr*PITCH + c0]     = *(const uint4*)&arow[kt + c0];
            *(uint4*)&sA[lr*PITCH + c0 + 8] = *(const uint4*)&arow[kt + c0 + 8];
            // B is fp32: load 16 floats, pack to bf16
            float4 b0 = *(const float4*)&brow[kt + c0];
            float4 b1 = *(const float4*)&brow[kt + c0 + 4];
            float4 b2 = *(const float4*)&brow[kt + c0 + 8];
            float4 b3 = *(const float4*)&brow[kt + c0 + 12];
            *(uint4*)&sB[lr*PITCH + c0]     = pack8(b0, b1);
            *(uint4*)&sB[lr*PITCH + c0 + 8] = pack8(b2, b3);
        }
        __syncthreads();
#pragma unroll
        for (int ks = 0; ks < 64; ks += 32) {
            bf16x8 af = *(const bf16x8*)&sA[(wv*16 + l15)*PITCH + ks + kq];
#pragma unroll
            for (int nt = 0; nt < 4; ++nt) {
                bf16x8 bf = *(const bf16x8*)&sB[(nt*16 + l15)*PITCH + ks + kq];
                acc[nt] = __builtin_amdgcn_mfma_f32_16x16x32_bf16(af, bf, acc[nt], 0, 0, 0);
            }
        }
    }
#pragma unroll
    for (int nt = 0; nt < 4; ++nt) {
#pragma unroll
        for (int r = 0; r < 4; ++r) {
            int ml = wv*16 + (lane >> 4)*4 + r;
            if (ml < nv) {
                u32 ent = sEnt[ml];
                u32 tk = ent >> 3;
                float cw = wslot[tk * SLOTS + (ent & 7u)];
                atomicAdd(&out[(size_t)tk * DIM + n0 + nt*16 + l15],
                          cw * acc[nt][r]);
            }
        }
    }
}

// NOTE: gemm1 sA staging wastes nothing: c0 covers 0..63 fp32 of the 64-wide
// K-chunk; sA rows only use [0,64) of the 72-elem pitch (pad stays unwritten).

// ------------------------------------------------------------------ launch --
extern "C" void kernel_launch(void* const* d_in, const int* in_sizes, int n_in,
                              void* d_out, int out_size, void* d_ws, size_t ws_size,
                              hipStream_t stream)
{
    (void)n_in; (void)out_size; (void)ws_size;
    const float* x    = (const float*)d_in[0];
    const float* gate = (const float*)d_in[1];
    const float* w1   = (const float*)d_in[2];
    const float* w3   = (const float*)d_in[3];
    const float* w2   = (const float*)d_in[4];
    const float* sw1  = (const float*)d_in[5];
    const float* sw3  = (const float*)d_in[6];
    const float* sw2  = (const float*)d_in[7];
    float* out = (float*)d_out;
    const int T = in_sizes[0] / DIM;     // 2048

    char* w = (char*)d_ws;
    int*  counts = (int*)(w);            // 17 ints, zeroed each call
    int*  tileE  = (int*)(w + 256);
    int*  tileR0 = (int*)(w + 1280);
    int*  tileNV = (int*)(w + 2304);
    int*  tot    = (int*)(w + 3328);
    size_t off = 4096;
    u32*   pairs = (u32*)(w + off);  off += (size_t)(NEXP + 1) * T * 4;  // 139 KB
    float* wslot = (float*)(w + off); off += (size_t)T * SLOTS * 4;      // 40 KB
    off = (off + 255) & ~(size_t)255;
    u16*   actb  = (u16*)(w + off);  off += (size_t)T * SLOTS * HID * 2; // 10.5 MB
    // total ws use ~10.7 MB

    hipMemsetAsync(w, 0, 256, stream);                                  // counts
    hipMemsetAsync(out, 0, (size_t)T * DIM * sizeof(float), stream);    // fp32 acc target

    moe_router<<<T, 64, 0, stream>>>(x, gate, counts, pairs, wslot, T);
    moe_build_tiles<<<1, 1, 0, stream>>>(counts, tileE, tileR0, tileNV, tot, T);

    moe_gemm1<<<dim3(HID / 64, MAXTILES), 256, 0, stream>>>(
        x, w1, w3, sw1, sw3, pairs, tileE, tileR0, tileNV, tot, actb, T);
    moe_gemm2<<<dim3(DIM / 64, MAXTILES), 256, 0, stream>>>(
        actb, w2, sw2, pairs, wslot, tileE, tileR0, tileNV, tot, out, T);
}

// Round 4
// 303.775 us; speedup vs baseline: 1.0952x; 1.0952x over previous
//
#include <hip/hip_runtime.h>

#define DIM   1024
#define HID   512
#define NEXP  16
#define TOPK  4
#define SLOTS 5
#define BM    64
#define PITCH 72   // 64 + 8 bf16 pad: keeps ds_read_b128 off 4-way+ bank conflicts
#define MAXTILES 176

typedef unsigned short u16;
typedef unsigned int   u32;
typedef short bf16x8 __attribute__((ext_vector_type(8)));
typedef float f32x4  __attribute__((ext_vector_type(4)));

__device__ __forceinline__ u16 f2bf(float f) {
    union { float f; u32 i; } v; v.f = f;
    u32 lsb = (v.i >> 16) & 1u;
    v.i += 0x7fffu + lsb;              // round-to-nearest-even
    return (u16)(v.i >> 16);
}
// pack 8 fp32 -> 8 bf16 in a uint4
__device__ __forceinline__ uint4 pack8(float4 a, float4 b) {
    uint4 r;
    r.x = (u32)f2bf(a.x) | ((u32)f2bf(a.y) << 16);
    r.y = (u32)f2bf(a.z) | ((u32)f2bf(a.w) << 16);
    r.z = (u32)f2bf(b.x) | ((u32)f2bf(b.y) << 16);
    r.w = (u32)f2bf(b.z) | ((u32)f2bf(b.w) << 16);
    return r;
}

// ------------------------------------------------------------- fp32->bf16 ---
__global__ __launch_bounds__(256) void cvt_bf16(
    const float* __restrict__ src, u16* __restrict__ dst, int n8)
{
    int i = blockIdx.x * 256 + threadIdx.x;
    if (i >= n8) return;
    float4 a = ((const float4*)src)[i * 2];
    float4 b = ((const float4*)src)[i * 2 + 1];
    ((uint4*)dst)[i] = pack8(a, b);
}

// ---------------------------------------------------------------- router ----
// 1 wave per token: 16 logits via butterfly reduce -> top4 (strict >, ties to
// lowest index = lax.top_k) -> softmax over selected 4 (== renormalized topk).
__global__ __launch_bounds__(64) void moe_router(
    const float* __restrict__ x, const float* __restrict__ gate,
    int* __restrict__ counts, u32* __restrict__ pairs,
    float* __restrict__ wslot, int T)
{
    const int t = blockIdx.x;
    const int lane = threadIdx.x;
    const float* xrow = x + (size_t)t * DIM;
    float xr[16];
#pragma unroll
    for (int j = 0; j < 16; ++j) xr[j] = xrow[lane + 64 * j];

    float logit[NEXP];
#pragma unroll
    for (int e = 0; e < NEXP; ++e) {
        const float* g = gate + (size_t)e * DIM;
        float s = 0.f;
#pragma unroll
        for (int j = 0; j < 16; ++j) s += xr[j] * g[lane + 64 * j];
#pragma unroll
        for (int off = 32; off > 0; off >>= 1) s += __shfl_xor(s, off);
        logit[e] = s;   // butterfly: identical across all 64 lanes
    }

    float v[NEXP];
#pragma unroll
    for (int e = 0; e < NEXP; ++e) v[e] = logit[e];
    int idx[TOPK]; float lv[TOPK];
#pragma unroll
    for (int r = 0; r < TOPK; ++r) {
        int be = 0; float bv = v[0];
        for (int e = 1; e < NEXP; ++e) { if (v[e] > bv) { bv = v[e]; be = e; } }
        idx[r] = be; lv[r] = bv; v[be] = -3.0e38f;
    }
    float wk[TOPK]; float wsum = 0.f;
#pragma unroll
    for (int r = 0; r < TOPK; ++r) { wk[r] = __expf(lv[r] - lv[0]); wsum += wk[r]; }
#pragma unroll
    for (int r = 0; r < TOPK; ++r) wk[r] /= wsum;

    if (lane < TOPK) {
        int e = idx[lane];
        int slot = atomicAdd(&counts[e], 1);
        if (slot < T) pairs[(size_t)e * T + slot] = ((u32)t << 3) | (u32)lane;
        wslot[t * SLOTS + lane] = wk[lane];
    } else if (lane == TOPK) {
        pairs[(size_t)NEXP * T + t] = ((u32)t << 3) | 4u;   // shared expert
        wslot[t * SLOTS + 4] = 1.0f;
    }
}

// ---------------------------------------------------------- tile builder ----
__global__ void moe_build_tiles(const int* __restrict__ counts,
    int* __restrict__ tileE, int* __restrict__ tileR0, int* __restrict__ tileNV,
    int* __restrict__ tot, int T)
{
    if (threadIdx.x != 0 || blockIdx.x != 0) return;
    int n = 0;
    for (int e = 0; e <= NEXP; ++e) {
        int c = (e == NEXP) ? T : counts[e];
        c = min(max(c, 0), T);                 // clamp vs corruption
        for (int r = 0; r < c && n < MAXTILES; r += BM) {
            tileE[n] = e; tileR0[n] = r;
            tileNV[n] = min(BM, c - r);
            ++n;
        }
    }
    *tot = n;
}

// ===================== FAST PATH: all-bf16 operands ========================
// gemm1_b: act[t*5+slot][0:512] = silu(x.W1_e^T) * (x.W3_e^T); e=16 = shared.
__global__ __launch_bounds__(256) void moe_gemm1_b(
    const u16* __restrict__ xb,
    const u16* __restrict__ w1c, const u16* __restrict__ w3c,
    const u32* __restrict__ pairs,
    const int* __restrict__ tileE, const int* __restrict__ tileR0,
    const int* __restrict__ tileNV, const int* __restrict__ tot,
    u16* __restrict__ act, int T)
{
    const int tile = blockIdx.y;
    if (tile >= min(*tot, MAXTILES)) return;
    const int e  = min(max(tileE[tile], 0), NEXP);
    const int r0 = min(max(tileR0[tile], 0), T - 1);
    const int nv = min(max(tileNV[tile], 0), min(BM, T - r0));
    const int n0 = blockIdx.x * 64;

    const u16* W1 = w1c + (size_t)e * HID * DIM;
    const u16* W3 = w3c + (size_t)e * HID * DIM;

    __shared__ __align__(16) u16 sA [64 * PITCH];
    __shared__ __align__(16) u16 sB1[64 * PITCH];
    __shared__ __align__(16) u16 sB3[64 * PITCH];
    __shared__ u32 sEnt[64];

    const int tid = threadIdx.x;
    if (tid < 64) {
        u32 ent = (tid < nv) ? pairs[(size_t)e * T + r0 + tid] : 0u;
        u32 tk = ent >> 3, sl = ent & 7u;
        if (tk >= (u32)T) tk = 0;
        if (sl >= SLOTS)  sl = 0;
        sEnt[tid] = (tk << 3) | sl;
    }
    __syncthreads();

    const int lr = tid >> 2;            // staging row 0..63
    const int c0 = (tid & 3) * 16;      // 16 bf16 elems (two uint4) per thread
    const u32 entA = sEnt[lr];
    const u16* xrow  = xb + (size_t)(entA >> 3) * DIM;
    const u16* b1row = W1 + (size_t)(n0 + lr) * DIM;
    const u16* b3row = W3 + (size_t)(n0 + lr) * DIM;

    const int wv   = tid >> 6;          // wave 0..3 -> M rows [wv*16, +16)
    const int lane = tid & 63;
    const int l15  = lane & 15;
    const int kq   = (lane >> 4) * 8;   // A/B frag: k = quad*8 + j

    f32x4 acc1[4], acc3[4];
#pragma unroll
    for (int i = 0; i < 4; ++i) { acc1[i] = (f32x4){0,0,0,0}; acc3[i] = (f32x4){0,0,0,0}; }

    for (int kt = 0; kt < DIM; kt += 64) {
        __syncthreads();
        *(uint4*)&sA [lr*PITCH + c0]     = *(const uint4*)&xrow [kt + c0];
        *(uint4*)&sA [lr*PITCH + c0 + 8] = *(const uint4*)&xrow [kt + c0 + 8];
        *(uint4*)&sB1[lr*PITCH + c0]     = *(const uint4*)&b1row[kt + c0];
        *(uint4*)&sB1[lr*PITCH + c0 + 8] = *(const uint4*)&b1row[kt + c0 + 8];
        *(uint4*)&sB3[lr*PITCH + c0]     = *(const uint4*)&b3row[kt + c0];
        *(uint4*)&sB3[lr*PITCH + c0 + 8] = *(const uint4*)&b3row[kt + c0 + 8];
        __syncthreads();
#pragma unroll
        for (int ks = 0; ks < 64; ks += 32) {
            bf16x8 af = *(const bf16x8*)&sA[(wv*16 + l15)*PITCH + ks + kq];
#pragma unroll
            for (int nt = 0; nt < 4; ++nt) {
                bf16x8 b1 = *(const bf16x8*)&sB1[(nt*16 + l15)*PITCH + ks + kq];
                bf16x8 b3 = *(const bf16x8*)&sB3[(nt*16 + l15)*PITCH + ks + kq];
                acc1[nt] = __builtin_amdgcn_mfma_f32_16x16x32_bf16(af, b1, acc1[nt], 0, 0, 0);
                acc3[nt] = __builtin_amdgcn_mfma_f32_16x16x32_bf16(af, b3, acc3[nt], 0, 0, 0);
            }
        }
    }
    // C/D layout (m89-verified): col = lane&15, row = (lane>>4)*4 + reg
#pragma unroll
    for (int nt = 0; nt < 4; ++nt) {
#pragma unroll
        for (int r = 0; r < 4; ++r) {
            int ml = wv*16 + (lane >> 4)*4 + r;
            if (ml < nv) {
                float h1 = acc1[nt][r], h3 = acc3[nt][r];
                float a = (h1 / (1.f + __expf(-h1))) * h3;   // silu(h1)*h3
                u32 ent = sEnt[ml];
                size_t sidx = (size_t)(ent >> 3) * SLOTS + (ent & 7u);
                act[sidx * HID + n0 + nt*16 + l15] = f2bf(a);
            }
        }
    }
}

// gemm2_b: out[t][:] += wslot[t][slot] * (act[t*5+slot] . W2_e^T)
__global__ __launch_bounds__(256) void moe_gemm2_b(
    const u16* __restrict__ act, const u16* __restrict__ w2c,
    const u32* __restrict__ pairs, const float* __restrict__ wslot,
    const int* __restrict__ tileE, const int* __restrict__ tileR0,
    const int* __restrict__ tileNV, const int* __restrict__ tot,
    float* __restrict__ out, int T)
{
    const int tile = blockIdx.y;
    if (tile >= min(*tot, MAXTILES)) return;
    const int e  = min(max(tileE[tile], 0), NEXP);
    const int r0 = min(max(tileR0[tile], 0), T - 1);
    const int nv = min(max(tileNV[tile], 0), min(BM, T - r0));
    const int n0 = blockIdx.x * 64;

    const u16* W2 = w2c + (size_t)e * DIM * HID;

    __shared__ __align__(16) u16 sA[64 * PITCH];
    __shared__ __align__(16) u16 sB[64 * PITCH];
    __shared__ u32 sEnt[64];

    const int tid = threadIdx.x;
    if (tid < 64) {
        u32 ent = (tid < nv) ? pairs[(size_t)e * T + r0 + tid] : 0u;
        u32 tk = ent >> 3, sl = ent & 7u;
        if (tk >= (u32)T) tk = 0;
        if (sl >= SLOTS)  sl = 0;
        sEnt[tid] = (tk << 3) | sl;
    }
    __syncthreads();

    const int lr = tid >> 2;
    const int c0 = (tid & 3) * 16;
    const u32 entA = sEnt[lr];
    const u16* arow = act + ((size_t)(entA >> 3) * SLOTS + (entA & 7u)) * HID;
    const u16* brow = W2 + (size_t)(n0 + lr) * HID;

    const int wv   = tid >> 6;
    const int lane = tid & 63;
    const int l15  = lane & 15;
    const int kq   = (lane >> 4) * 8;

    f32x4 acc[4];
#pragma unroll
    for (int i = 0; i < 4; ++i) acc[i] = (f32x4){0,0,0,0};

    for (int kt = 0; kt < HID; kt += 64) {
        __syncthreads();
        *(uint4*)&sA[lr*PITCH + c0]     = *(const uint4*)&arow[kt + c0];
        *(uint4*)&sA[lr*PITCH + c0 + 8] = *(const uint4*)&arow[kt + c0 + 8];
        *(uint4*)&sB[lr*PITCH + c0]     = *(const uint4*)&brow[kt + c0];
        *(uint4*)&sB[lr*PITCH + c0 + 8] = *(const uint4*)&brow[kt + c0 + 8];
        __syncthreads();
#pragma unroll
        for (int ks = 0; ks < 64; ks += 32) {
            bf16x8 af = *(const bf16x8*)&sA[(wv*16 + l15)*PITCH + ks + kq];
#pragma unroll
            for (int nt = 0; nt < 4; ++nt) {
                bf16x8 bf = *(const bf16x8*)&sB[(nt*16 + l15)*PITCH + ks + kq];
                acc[nt] = __builtin_amdgcn_mfma_f32_16x16x32_bf16(af, bf, acc[nt], 0, 0, 0);
            }
        }
    }
#pragma unroll
    for (int nt = 0; nt < 4; ++nt) {
#pragma unroll
        for (int r = 0; r < 4; ++r) {
            int ml = wv*16 + (lane >> 4)*4 + r;
            if (ml < nv) {
                u32 ent = sEnt[ml];
                u32 tk = ent >> 3;
                float cw = wslot[tk * SLOTS + (ent & 7u)];
                atomicAdd(&out[(size_t)tk * DIM + n0 + nt*16 + l15],
                          cw * acc[nt][r]);
            }
        }
    }
}

// ================= FALLBACK (round-3, passing): fp32 in-loop convert =======
__global__ __launch_bounds__(256) void moe_gemm1_fb(
    const float* __restrict__ x,
    const float* __restrict__ w1, const float* __restrict__ w3,
    const float* __restrict__ sw1, const float* __restrict__ sw3,
    const u32* __restrict__ pairs,
    const int* __restrict__ tileE, const int* __restrict__ tileR0,
    const int* __restrict__ tileNV, const int* __restrict__ tot,
    u16* __restrict__ act, int T)
{
    const int tile = blockIdx.y;
    if (tile >= min(*tot, MAXTILES)) return;
    const int e  = min(max(tileE[tile], 0), NEXP);
    const int r0 = min(max(tileR0[tile], 0), T - 1);
    const int nv = min(max(tileNV[tile], 0), min(BM, T - r0));
    const int n0 = blockIdx.x * 64;
    const float* W1 = (e < NEXP) ? (w1 + (size_t)e * HID * DIM) : sw1;
    const float* W3 = (e < NEXP) ? (w3 + (size_t)e * HID * DIM) : sw3;
    __shared__ __align__(16) u16 sA [64 * PITCH];
    __shared__ __align__(16) u16 sB1[64 * PITCH];
    __shared__ __align__(16) u16 sB3[64 * PITCH];
    __shared__ u32 sEnt[64];
    const int tid = threadIdx.x;
    if (tid < 64) {
        u32 ent = (tid < nv) ? pairs[(size_t)e * T + r0 + tid] : 0u;
        u32 tk = ent >> 3, sl = ent & 7u;
        if (tk >= (u32)T) tk = 0;
        if (sl >= SLOTS)  sl = 0;
        sEnt[tid] = (tk << 3) | sl;
    }
    __syncthreads();
    const int lr = tid >> 2;
    const int c0 = (tid & 3) * 16;
    const u32 entA = sEnt[lr];
    const float* xrow  = x  + (size_t)(entA >> 3) * DIM;
    const float* b1row = W1 + (size_t)(n0 + lr) * DIM;
    const float* b3row = W3 + (size_t)(n0 + lr) * DIM;
    const int wv = tid >> 6, lane = tid & 63, l15 = lane & 15, kq = (lane >> 4) * 8;
    f32x4 acc1[4], acc3[4];
#pragma unroll
    for (int i = 0; i < 4; ++i) { acc1[i] = (f32x4){0,0,0,0}; acc3[i] = (f32x4){0,0,0,0}; }
    for (int kt = 0; kt < DIM; kt += 64) {
        __syncthreads();
        {
            float4 a0 = *(const float4*)&xrow [kt + c0];
            float4 a1 = *(const float4*)&xrow [kt + c0 + 4];
            float4 a2 = *(const float4*)&xrow [kt + c0 + 8];
            float4 a3 = *(const float4*)&xrow [kt + c0 + 12];
            *(uint4*)&sA [lr*PITCH + c0]     = pack8(a0, a1);
            *(uint4*)&sA [lr*PITCH + c0 + 8] = pack8(a2, a3);
            float4 b0 = *(const float4*)&b1row[kt + c0];
            float4 b1 = *(const float4*)&b1row[kt + c0 + 4];
            float4 b2 = *(const float4*)&b1row[kt + c0 + 8];
            float4 b3 = *(const float4*)&b1row[kt + c0 + 12];
            *(uint4*)&sB1[lr*PITCH + c0]     = pack8(b0, b1);
            *(uint4*)&sB1[lr*PITCH + c0 + 8] = pack8(b2, b3);
            float4 d0 = *(const float4*)&b3row[kt + c0];
            float4 d1 = *(const float4*)&b3row[kt + c0 + 4];
            float4 d2 = *(const float4*)&b3row[kt + c0 + 8];
            float4 d3 = *(const float4*)&b3row[kt + c0 + 12];
            *(uint4*)&sB3[lr*PITCH + c0]     = pack8(d0, d1);
            *(uint4*)&sB3[lr*PITCH + c0 + 8] = pack8(d2, d3);
        }
        __syncthreads();
#pragma unroll
        for (int ks = 0; ks < 64; ks += 32) {
            bf16x8 af = *(const bf16x8*)&sA[(wv*16 + l15)*PITCH + ks + kq];
#pragma unroll
            for (int nt = 0; nt < 4; ++nt) {
                bf16x8 b1 = *(const bf16x8*)&sB1[(nt*16 + l15)*PITCH + ks + kq];
                bf16x8 b3 = *(const bf16x8*)&sB3[(nt*16 + l15)*PITCH + ks + kq];
                acc1[nt] = __builtin_amdgcn_mfma_f32_16x16x32_bf16(af, b1, acc1[nt], 0, 0, 0);
                acc3[nt] = __builtin_amdgcn_mfma_f32_16x16x32_bf16(af, b3, acc3[nt], 0, 0, 0);
            }
        }
    }
#pragma unroll
    for (int nt = 0; nt < 4; ++nt) {
#pragma unroll
        for (int r = 0; r < 4; ++r) {
            int ml = wv*16 + (lane >> 4)*4 + r;
            if (ml < nv) {
                float h1 = acc1[nt][r], h3 = acc3[nt][r];
                float a = (h1 / (1.f + __expf(-h1))) * h3;
                u32 ent = sEnt[ml];
                size_t sidx = (size_t)(ent >> 3) * SLOTS + (ent & 7u);
                act[sidx * HID + n0 + nt*16 + l15] = f2bf(a);
            }
        }
    }
}

__global__ __launch_bounds__(256) void moe_gemm2_fb(
    const u16* __restrict__ act,
    const float* __restrict__ w2, const float* __restrict__ sw2,
    const u32* __restrict__ pairs, const float* __restrict__ wslot,
    const int* __restrict__ tileE, const int* __restrict__ tileR0,
    const int* __restrict__ tileNV, const int* __restrict__ tot,
    float* __restrict__ out, int T)
{
    const int tile = blockIdx.y;
    if (tile >= min(*tot, MAXTILES)) return;
    const int e  = min(max(tileE[tile], 0), NEXP);
    const int r0 = min(max(tileR0[tile], 0), T - 1);
    const int nv = min(max(tileNV[tile], 0), min(BM, T - r0));
    const int n0 = blockIdx.x * 64;
    const float* W2 = (e < NEXP) ? (w2 + (size_t)e * DIM * HID) : sw2;
    __shared__ __align__(16) u16 sA[64 * PITCH];
    __shared__ __align__(16) u16 sB[64 * PITCH];
    __shared__ u32 sEnt[64];
    const int tid = threadIdx.x;
    if (tid < 64) {
        u32 ent = (tid < nv) ? pairs[(size_t)e * T + r0 + tid] : 0u;
        u32 tk = ent >> 3, sl = ent & 7u;
        if (tk >= (u32)T) tk = 0;
        if (sl >= SLOTS)  sl = 0;
        sEnt[tid] = (tk << 3) | sl;
    }
    __syncthreads();
    const int lr = tid >> 2;
    const int c0 = (tid & 3) * 16;
    const u32 entA = sEnt[lr];
    const u16*   arow = act + ((size_t)(entA >> 3) * SLOTS + (entA & 7u)) * HID;
    const float* brow = W2 + (size_t)(n0 + lr) * HID;
    const int wv = tid >> 6, lane = tid & 63, l15 = lane & 15, kq = (lane >> 4) * 8;
    f32x4 acc[4];
#pragma unroll
    for (int i = 0; i < 4; ++i) acc[i] = (f32x4){0,0,0,0};
    for (int kt = 0; kt < HID; kt += 64) {
        __syncthreads();
        {
            *(uint4*)&sA[lr*PITCH + c0]     = *(const uint4*)&arow[kt + c0];
            *(uint4*)&sA[lr*PITCH + c0 + 8] = *(const uint4*)&arow[kt + c0 + 8];
            float4 b0 = *(const float4*)&brow[kt + c0];
            float4 b1 = *(const float4*)&brow[kt + c0 + 4];
            float4 b2 = *(const float4*)&brow[kt + c0 + 8];
            float4 b3 = *(const float4*)&brow[kt + c0 + 12];
            *(uint4*)&sB[lr*PITCH + c0]     = pack8(b0, b1);
            *(uint4*)&sB[lr*PITCH + c0 + 8] = pack8(b2, b3);
        }
        __syncthreads();
#pragma unroll
        for (int ks = 0; ks < 64; ks += 32) {
            bf16x8 af = *(const bf16x8*)&sA[(wv*16 + l15)*PITCH + ks + kq];
#pragma unroll
            for (int nt = 0; nt < 4; ++nt) {
                bf16x8 bf = *(const bf16x8*)&sB[(nt*16 + l15)*PITCH + ks + kq];
                acc[nt] = __builtin_amdgcn_mfma_f32_16x16x32_bf16(af, bf, acc[nt], 0, 0, 0);
            }
        }
    }
#pragma unroll
    for (int nt = 0; nt < 4; ++nt) {
#pragma unroll
        for (int r = 0; r < 4; ++r) {
            int ml = wv*16 + (lane >> 4)*4 + r;
            if (ml < nv) {
                u32 ent = sEnt[ml];
                u32 tk = ent >> 3;
                float cw = wslot[tk * SLOTS + (ent & 7u)];
                atomicAdd(&out[(size_t)tk * DIM + n0 + nt*16 + l15],
                          cw * acc[nt][r]);
            }
        }
    }
}

// ------------------------------------------------------------------ launch --
extern "C" void kernel_launch(void* const* d_in, const int* in_sizes, int n_in,
                              void* d_out, int out_size, void* d_ws, size_t ws_size,
                              hipStream_t stream)
{
    (void)n_in; (void)out_size;
    const float* x    = (const float*)d_in[0];
    const float* gate = (const float*)d_in[1];
    const float* w1   = (const float*)d_in[2];
    const float* w3   = (const float*)d_in[3];
    const float* w2   = (const float*)d_in[4];
    const float* sw1  = (const float*)d_in[5];
    const float* sw3  = (const float*)d_in[6];
    const float* sw2  = (const float*)d_in[7];
    float* out = (float*)d_out;
    const int T = in_sizes[0] / DIM;     // 2048

    char* w = (char*)d_ws;
    int*  counts = (int*)(w);            // zeroed each call
    int*  tileE  = (int*)(w + 256);
    int*  tileR0 = (int*)(w + 1280);
    int*  tileNV = (int*)(w + 2304);
    int*  tot    = (int*)(w + 3328);
    size_t off = 4096;
    u32*   pairs = (u32*)(w + off);  off += (size_t)(NEXP + 1) * T * 4;
    float* wslot = (float*)(w + off); off += (size_t)T * SLOTS * 4;
    off = (off + 255) & ~(size_t)255;
    u16*   actb  = (u16*)(w + off);  off += (size_t)T * SLOTS * HID * 2;
    off = (off + 255) & ~(size_t)255;

    // fast-path extra buffers (bf16 weight/x copies)
    const size_t EW13 = (size_t)(NEXP + 1) * HID * DIM;   // W1c / W3c elems
    const size_t EW2  = (size_t)(NEXP + 1) * DIM * HID;   // W2c elems
    u16* xb  = (u16*)(w + off);
    u16* W1c = xb  + (size_t)T * DIM;
    u16* W3c = W1c + EW13;
    u16* W2c = W3c + EW13;
    const size_t need = off + ((size_t)T * DIM + 2 * EW13 + EW2) * 2;
    const bool fast = ws_size >= need;   // ws_size constant across calls -> graph-safe

    hipMemsetAsync(w, 0, 256, stream);                                // counts
    hipMemsetAsync(out, 0, (size_t)T * DIM * sizeof(float), stream);  // acc target

    moe_router<<<T, 64, 0, stream>>>(x, gate, counts, pairs, wslot, T);
    moe_build_tiles<<<1, 1, 0, stream>>>(counts, tileE, tileR0, tileNV, tot, T);

    if (fast) {
        const int nW = (int)(NEXP * HID * DIM / 8);     // per-expert-stack chunks
        const int nS = (int)(HID * DIM / 8);
        cvt_bf16<<<(nW + 255) / 256, 256, 0, stream>>>(w1,  W1c, nW);
        cvt_bf16<<<(nS + 255) / 256, 256, 0, stream>>>(sw1, W1c + (size_t)NEXP * HID * DIM, nS);
        cvt_bf16<<<(nW + 255) / 256, 256, 0, stream>>>(w3,  W3c, nW);
        cvt_bf16<<<(nS + 255) / 256, 256, 0, stream>>>(sw3, W3c + (size_t)NEXP * HID * DIM, nS);
        cvt_bf16<<<(nW + 255) / 256, 256, 0, stream>>>(w2,  W2c, nW);
        cvt_bf16<<<(nS + 255) / 256, 256, 0, stream>>>(sw2, W2c + (size_t)NEXP * DIM * HID, nS);
        const int nX = T * DIM / 8;
        cvt_bf16<<<(nX + 255) / 256, 256, 0, stream>>>(x, xb, nX);

        moe_gemm1_b<<<dim3(HID / 64, MAXTILES), 256, 0, stream>>>(
            xb, W1c, W3c, pairs, tileE, tileR0, tileNV, tot, actb, T);
        moe_gemm2_b<<<dim3(DIM / 64, MAXTILES), 256, 0, stream>>>(
            actb, W2c, pairs, wslot, tileE, tileR0, tileNV, tot, out, T);
    } else {
        moe_gemm1_fb<<<dim3(HID / 64, MAXTILES), 256, 0, stream>>>(
            x, w1, w3, sw1, sw3, pairs, tileE, tileR0, tileNV, tot, actb, T);
        moe_gemm2_fb<<<dim3(DIM / 64, MAXTILES), 256, 0, stream>>>(
            actb, w2, sw2, pairs, wslot, tileE, tileR0, tileNV, tot, out, T);
    }
}

// Round 5
// 262.177 us; speedup vs baseline: 1.2689x; 1.1587x over previous
//
#include <hip/hip_runtime.h>

#define DIM   1024
#define HID   512
#define NEXP  16
#define TOPK  4
#define SLOTS 5
#define PITCH 72     // 64 + 8 bf16 pad: row stride 36 words -> 2-way bank alias (free, m136)
#define MAXT128 96   // sum ceil(c_e/128) <= 8192/128 + 16 + 2048/128 = 96

typedef unsigned short u16;
typedef unsigned int   u32;
typedef short bf16x8 __attribute__((ext_vector_type(8)));
typedef float f32x4  __attribute__((ext_vector_type(4)));

__device__ __forceinline__ float bf2f(u16 u) {
    union { u32 i; float f; } v; v.i = ((u32)u) << 16; return v.f;
}
__device__ __forceinline__ u16 f2bf(float f) {
    union { float f; u32 i; } v; v.f = f;
    u32 lsb = (v.i >> 16) & 1u;
    v.i += 0x7fffu + lsb;              // round-to-nearest-even
    return (u16)(v.i >> 16);
}
__device__ __forceinline__ uint4 pack8(float4 a, float4 b) {
    uint4 r;
    r.x = (u32)f2bf(a.x) | ((u32)f2bf(a.y) << 16);
    r.y = (u32)f2bf(a.z) | ((u32)f2bf(a.w) << 16);
    r.z = (u32)f2bf(b.x) | ((u32)f2bf(b.y) << 16);
    r.w = (u32)f2bf(b.z) | ((u32)f2bf(b.w) << 16);
    return r;
}

// segment boundaries (8-elem chunks) in the contiguous bf16 dst buffer:
// [w1 | sw1 | w3 | sw3 | w2 | sw2 | x]  -> W1c/W3c/W2c each get expert 16 = shared
#define CW ((size_t)NEXP * HID * DIM / 8)   // 1,048,576
#define CS ((size_t)HID * DIM / 8)          //    65,536
#define SEG_B0 (CW)
#define SEG_B1 (SEG_B0 + CS)
#define SEG_B2 (SEG_B1 + CW)
#define SEG_B3 (SEG_B2 + CS)
#define SEG_B4 (SEG_B3 + CW)
#define SEG_B5 (SEG_B4 + CS)                // 3,342,336 chunks (weights only)

// ------------------------------------------------------------------- prep ---
// blocks [0, nCvt): fp32->bf16 of all weights + x into one contiguous buffer.
// blocks [nCvt, nCvt+T): router for token t = blk - nCvt (first wave only).
__global__ __launch_bounds__(256) void moe_prep(
    const float* __restrict__ x,    const float* __restrict__ gate,
    const float* __restrict__ w1,   const float* __restrict__ w3,
    const float* __restrict__ w2,   const float* __restrict__ sw1,
    const float* __restrict__ sw3,  const float* __restrict__ sw2,
    u16* __restrict__ dst, int nCvt,
    int* __restrict__ counts, u32* __restrict__ pairs,
    float* __restrict__ wslot, int T)
{
    const int blk = blockIdx.x;
    if (blk < nCvt) {
        const size_t c = (size_t)blk * 256 + threadIdx.x;   // chunk id
        const float* src; size_t loc;
        if      (c < SEG_B0) { src = w1;  loc = c; }
        else if (c < SEG_B1) { src = sw1; loc = c - SEG_B0; }
        else if (c < SEG_B2) { src = w3;  loc = c - SEG_B1; }
        else if (c < SEG_B3) { src = sw3; loc = c - SEG_B2; }
        else if (c < SEG_B4) { src = w2;  loc = c - SEG_B3; }
        else if (c < SEG_B5) { src = sw2; loc = c - SEG_B4; }
        else                 { src = x;   loc = c - SEG_B5; }
        float4 a = ((const float4*)src)[loc * 2];
        float4 b = ((const float4*)src)[loc * 2 + 1];
        ((uint4*)dst)[c] = pack8(a, b);
        return;
    }
    // ---- router: 1 wave per token ----
    const int lane = threadIdx.x;
    if (lane >= 64) return;
    const int t = blk - nCvt;
    const float* xrow = x + (size_t)t * DIM;
    float xr[16];
#pragma unroll
    for (int j = 0; j < 16; ++j) xr[j] = xrow[lane + 64 * j];

    float logit[NEXP];
#pragma unroll
    for (int e = 0; e < NEXP; ++e) {
        const float* g = gate + (size_t)e * DIM;
        float s = 0.f;
#pragma unroll
        for (int j = 0; j < 16; ++j) s += xr[j] * g[lane + 64 * j];
#pragma unroll
        for (int off = 32; off > 0; off >>= 1) s += __shfl_xor(s, off);
        logit[e] = s;   // identical across lanes
    }
    float v[NEXP];
#pragma unroll
    for (int e = 0; e < NEXP; ++e) v[e] = logit[e];
    int idx[TOPK]; float lv[TOPK];
#pragma unroll
    for (int r = 0; r < TOPK; ++r) {                 // strict > : lax.top_k ties
        int be = 0; float bv = v[0];
        for (int e = 1; e < NEXP; ++e) { if (v[e] > bv) { bv = v[e]; be = e; } }
        idx[r] = be; lv[r] = bv; v[be] = -3.0e38f;
    }
    float wk[TOPK]; float wsum = 0.f;
#pragma unroll
    for (int r = 0; r < TOPK; ++r) { wk[r] = __expf(lv[r] - lv[0]); wsum += wk[r]; }
#pragma unroll
    for (int r = 0; r < TOPK; ++r) wk[r] /= wsum;

    if (lane < TOPK) {
        int e = idx[lane];
        int slot = atomicAdd(&counts[e], 1);
        if (slot < T) pairs[(size_t)e * T + slot] = ((u32)t << 3) | (u32)lane;
        wslot[t * SLOTS + lane] = wk[lane];
    } else if (lane == TOPK) {
        pairs[(size_t)NEXP * T + t] = ((u32)t << 3) | 4u;   // shared expert
        wslot[t * SLOTS + 4] = 1.0f;
    }
}

// ---------------------------------------------------- tile builder (1 wave) -
__global__ __launch_bounds__(64) void moe_build_tiles(
    const int* __restrict__ counts,
    int* __restrict__ tileE, int* __restrict__ tileR0, int* __restrict__ tileNV,
    int* __restrict__ tot, int T)
{
    const int lane = threadIdx.x;
    int c = 0;
    if (lane < NEXP)       c = min(max(counts[lane], 0), T);
    else if (lane == NEXP) c = T;
    int nt = (c + 127) >> 7;
    int pre = nt;                                   // inclusive prefix over lanes
    for (int off = 1; off < 32; off <<= 1) {
        int vv = __shfl_up(pre, off);
        if (lane >= off) pre += vv;
    }
    int excl = pre - nt;
    if (lane <= NEXP) {
        for (int i = 0; i < nt; ++i) {
            int id = excl + i;
            if (id < MAXT128) {
                tileE[id] = lane; tileR0[id] = i << 7;
                tileNV[id] = min(128, c - (i << 7));
            }
        }
        if (lane == NEXP) *tot = min(excl + nt, MAXT128);
    }
}

// ------------------------------------------------------------------ gemm1 ---
// 128x64x64 tiles: act[t*5+slot][0:512] = silu(x.W1_e^T) * (x.W3_e^T)
__global__ __launch_bounds__(256) void moe_gemm1(
    const u16* __restrict__ xb,
    const u16* __restrict__ w1c, const u16* __restrict__ w3c,
    const u32* __restrict__ pairs,
    const int* __restrict__ tileE, const int* __restrict__ tileR0,
    const int* __restrict__ tileNV, const int* __restrict__ tot,
    u16* __restrict__ act, int T)
{
    const int tile = blockIdx.y;
    if (tile >= min(*tot, MAXT128)) return;
    const int e  = min(max(tileE[tile], 0), NEXP);
    const int r0 = min(max(tileR0[tile], 0), T - 1);
    const int nv = min(max(tileNV[tile], 0), min(128, T - r0));
    const int n0 = blockIdx.x * 64;

    const u16* W1 = w1c + (size_t)e * HID * DIM;
    const u16* W3 = w3c + (size_t)e * HID * DIM;

    __shared__ __align__(16) u16 sA [128 * PITCH];
    __shared__ __align__(16) u16 sB1[ 64 * PITCH];
    __shared__ __align__(16) u16 sB3[ 64 * PITCH];
    __shared__ u32 sEnt[128];

    const int tid = threadIdx.x;
    if (tid < 128) {
        u32 ent = (tid < nv) ? pairs[(size_t)e * T + r0 + tid] : 0u;
        u32 tk = ent >> 3, sl = ent & 7u;
        if (tk >= (u32)T) tk = 0;
        if (sl >= SLOTS)  sl = 0;
        sEnt[tid] = (tk << 3) | sl;
    }
    __syncthreads();

    const int ar = tid >> 1;            // sA staging row 0..127
    const int ac = (tid & 1) * 32;      // 32 elems (4 uint4) per thread
    const u16* xrow = xb + (size_t)(sEnt[ar] >> 3) * DIM;
    const int br = tid >> 2;            // sB row 0..63
    const int bc = (tid & 3) * 16;      // 16 elems (2 uint4)
    const u16* b1row = W1 + (size_t)(n0 + br) * DIM;
    const u16* b3row = W3 + (size_t)(n0 + br) * DIM;

    const int wv   = tid >> 6;          // wave -> M rows [wv*32, wv*32+32)
    const int lane = tid & 63;
    const int l15  = lane & 15;
    const int kq   = (lane >> 4) * 8;
    const int m0   = wv * 32;

    f32x4 acc1[2][4], acc3[2][4];
#pragma unroll
    for (int i = 0; i < 2; ++i)
#pragma unroll
        for (int j = 0; j < 4; ++j) { acc1[i][j] = (f32x4){0,0,0,0}; acc3[i][j] = (f32x4){0,0,0,0}; }

    for (int kt = 0; kt < DIM; kt += 64) {
        __syncthreads();
        *(uint4*)&sA [ar*PITCH + ac]      = *(const uint4*)&xrow [kt + ac];
        *(uint4*)&sA [ar*PITCH + ac +  8] = *(const uint4*)&xrow [kt + ac +  8];
        *(uint4*)&sA [ar*PITCH + ac + 16] = *(const uint4*)&xrow [kt + ac + 16];
        *(uint4*)&sA [ar*PITCH + ac + 24] = *(const uint4*)&xrow [kt + ac + 24];
        *(uint4*)&sB1[br*PITCH + bc]      = *(const uint4*)&b1row[kt + bc];
        *(uint4*)&sB1[br*PITCH + bc +  8] = *(const uint4*)&b1row[kt + bc + 8];
        *(uint4*)&sB3[br*PITCH + bc]      = *(const uint4*)&b3row[kt + bc];
        *(uint4*)&sB3[br*PITCH + bc +  8] = *(const uint4*)&b3row[kt + bc + 8];
        __syncthreads();
#pragma unroll
        for (int ks = 0; ks < 64; ks += 32) {
            bf16x8 a0 = *(const bf16x8*)&sA[(m0      + l15)*PITCH + ks + kq];
            bf16x8 a1 = *(const bf16x8*)&sA[(m0 + 16 + l15)*PITCH + ks + kq];
#pragma unroll
            for (int nt = 0; nt < 4; ++nt) {
                bf16x8 b1 = *(const bf16x8*)&sB1[(nt*16 + l15)*PITCH + ks + kq];
                bf16x8 b3 = *(const bf16x8*)&sB3[(nt*16 + l15)*PITCH + ks + kq];
                acc1[0][nt] = __builtin_amdgcn_mfma_f32_16x16x32_bf16(a0, b1, acc1[0][nt], 0, 0, 0);
                acc1[1][nt] = __builtin_amdgcn_mfma_f32_16x16x32_bf16(a1, b1, acc1[1][nt], 0, 0, 0);
                acc3[0][nt] = __builtin_amdgcn_mfma_f32_16x16x32_bf16(a0, b3, acc3[0][nt], 0, 0, 0);
                acc3[1][nt] = __builtin_amdgcn_mfma_f32_16x16x32_bf16(a1, b3, acc3[1][nt], 0, 0, 0);
            }
        }
    }
    // C/D: col = lane&15, row = (lane>>4)*4 + reg   (m89-verified)
#pragma unroll
    for (int mf = 0; mf < 2; ++mf)
#pragma unroll
    for (int nt = 0; nt < 4; ++nt)
#pragma unroll
    for (int r = 0; r < 4; ++r) {
        int ml = m0 + mf*16 + (lane >> 4)*4 + r;
        if (ml < nv) {
            float h1 = acc1[mf][nt][r], h3 = acc3[mf][nt][r];
            float a = (h1 / (1.f + __expf(-h1))) * h3;       // silu(h1)*h3
            u32 ent = sEnt[ml];
            size_t sidx = (size_t)(ent >> 3) * SLOTS + (ent & 7u);
            act[sidx * HID + n0 + nt*16 + l15] = f2bf(a);
        }
    }
}

// ------------------------------------------------------------------ gemm2 ---
// 128x128x64 tiles. useEout: eout[sidx][col] = w*(act.W2^T) else atomic to out.
__global__ __launch_bounds__(256) void moe_gemm2(
    const u16* __restrict__ act, const u16* __restrict__ w2c,
    const u32* __restrict__ pairs, const float* __restrict__ wslot,
    const int* __restrict__ tileE, const int* __restrict__ tileR0,
    const int* __restrict__ tileNV, const int* __restrict__ tot,
    u16* __restrict__ eout, float* __restrict__ out, int useEout, int T)
{
    const int tile = blockIdx.y;
    if (tile >= min(*tot, MAXT128)) return;
    const int e  = min(max(tileE[tile], 0), NEXP);
    const int r0 = min(max(tileR0[tile], 0), T - 1);
    const int nv = min(max(tileNV[tile], 0), min(128, T - r0));
    const int n0 = blockIdx.x * 128;

    const u16* W2 = w2c + (size_t)e * DIM * HID;

    __shared__ __align__(16) u16 sA[128 * PITCH];
    __shared__ __align__(16) u16 sB[128 * PITCH];
    __shared__ u32 sEnt[128];

    const int tid = threadIdx.x;
    if (tid < 128) {
        u32 ent = (tid < nv) ? pairs[(size_t)e * T + r0 + tid] : 0u;
        u32 tk = ent >> 3, sl = ent & 7u;
        if (tk >= (u32)T) tk = 0;
        if (sl >= SLOTS)  sl = 0;
        sEnt[tid] = (tk << 3) | sl;
    }
    __syncthreads();

    const int ar = tid >> 1;
    const int ac = (tid & 1) * 32;
    const u32 entA = sEnt[ar];
    const u16* arow = act + ((size_t)(entA >> 3) * SLOTS + (entA & 7u)) * HID;
    const u16* brow = W2 + (size_t)(n0 + ar) * HID;

    const int wv   = tid >> 6;
    const int lane = tid & 63;
    const int l15  = lane & 15;
    const int kq   = (lane >> 4) * 8;
    const int m0   = (wv & 1) * 64;     // wave 2x2 grid over 128x128
    const int nc0  = (wv >> 1) * 64;

    f32x4 acc[4][4];
#pragma unroll
    for (int i = 0; i < 4; ++i)
#pragma unroll
        for (int j = 0; j < 4; ++j) acc[i][j] = (f32x4){0,0,0,0};

    for (int kt = 0; kt < HID; kt += 64) {
        __syncthreads();
        *(uint4*)&sA[ar*PITCH + ac]      = *(const uint4*)&arow[kt + ac];
        *(uint4*)&sA[ar*PITCH + ac +  8] = *(const uint4*)&arow[kt + ac +  8];
        *(uint4*)&sA[ar*PITCH + ac + 16] = *(const uint4*)&arow[kt + ac + 16];
        *(uint4*)&sA[ar*PITCH + ac + 24] = *(const uint4*)&arow[kt + ac + 24];
        *(uint4*)&sB[ar*PITCH + ac]      = *(const uint4*)&brow[kt + ac];
        *(uint4*)&sB[ar*PITCH + ac +  8] = *(const uint4*)&brow[kt + ac +  8];
        *(uint4*)&sB[ar*PITCH + ac + 16] = *(const uint4*)&brow[kt + ac + 16];
        *(uint4*)&sB[ar*PITCH + ac + 24] = *(const uint4*)&brow[kt + ac + 24];
        __syncthreads();
#pragma unroll
        for (int ks = 0; ks < 64; ks += 32) {
            bf16x8 af[4], bf[4];
#pragma unroll
            for (int mf = 0; mf < 4; ++mf)
                af[mf] = *(const bf16x8*)&sA[(m0 + mf*16 + l15)*PITCH + ks + kq];
#pragma unroll
            for (int nf = 0; nf < 4; ++nf)
                bf[nf] = *(const bf16x8*)&sB[(nc0 + nf*16 + l15)*PITCH + ks + kq];
#pragma unroll
            for (int mf = 0; mf < 4; ++mf)
#pragma unroll
                for (int nf = 0; nf < 4; ++nf)
                    acc[mf][nf] = __builtin_amdgcn_mfma_f32_16x16x32_bf16(af[mf], bf[nf], acc[mf][nf], 0, 0, 0);
        }
    }
#pragma unroll
    for (int mf = 0; mf < 4; ++mf)
#pragma unroll
    for (int nf = 0; nf < 4; ++nf)
#pragma unroll
    for (int r = 0; r < 4; ++r) {
        int ml = m0 + mf*16 + (lane >> 4)*4 + r;
        if (ml < nv) {
            u32 ent = sEnt[ml];
            u32 tk = ent >> 3;
            float cw = wslot[tk * SLOTS + (ent & 7u)];
            int col = n0 + nc0 + nf*16 + l15;
            float v = cw * acc[mf][nf][r];
            if (useEout) {
                size_t sidx = (size_t)tk * SLOTS + (ent & 7u);
                eout[sidx * DIM + col] = f2bf(v);
            } else {
                atomicAdd(&out[(size_t)tk * DIM + col], v);
            }
        }
    }
}

// ---------------------------------------------------------------- combine ---
// out[t][col..col+3] = sum_s eout[t*5+s][col..col+3]  (weights pre-applied)
__global__ __launch_bounds__(256) void moe_combine(
    const u16* __restrict__ eout, float* __restrict__ out, int n4)
{
    int i = blockIdx.x * 256 + threadIdx.x;
    if (i >= n4) return;
    int o4 = i * 4;
    int t = o4 >> 10;                   // DIM = 1024
    int col = o4 & 1023;
    float a0 = 0.f, a1 = 0.f, a2 = 0.f, a3 = 0.f;
#pragma unroll
    for (int s = 0; s < SLOTS; ++s) {
        const u16* row = eout + ((size_t)t * SLOTS + s) * DIM + col;
        ushort4 u = *(const ushort4*)row;
        a0 += bf2f(u.x); a1 += bf2f(u.y); a2 += bf2f(u.z); a3 += bf2f(u.w);
    }
    float4* op = (float4*)(out + (size_t)t * DIM + col);
    *op = (float4){a0, a1, a2, a3};
}

// ------------------------------------------------------------------ launch --
extern "C" void kernel_launch(void* const* d_in, const int* in_sizes, int n_in,
                              void* d_out, int out_size, void* d_ws, size_t ws_size,
                              hipStream_t stream)
{
    (void)n_in; (void)out_size;
    const float* x    = (const float*)d_in[0];
    const float* gate = (const float*)d_in[1];
    const float* w1   = (const float*)d_in[2];
    const float* w3   = (const float*)d_in[3];
    const float* w2   = (const float*)d_in[4];
    const float* sw1  = (const float*)d_in[5];
    const float* sw3  = (const float*)d_in[6];
    const float* sw2  = (const float*)d_in[7];
    float* out = (float*)d_out;
    const int T = in_sizes[0] / DIM;     // 2048

    char* w = (char*)d_ws;
    int*  counts = (int*)(w);            // 256 B zeroed each call
    int*  tileE  = (int*)(w + 256);
    int*  tileR0 = (int*)(w + 256 + 512);
    int*  tileNV = (int*)(w + 256 + 1024);
    int*  tot    = (int*)(w + 256 + 1536);
    size_t off = 4096;
    u32*   pairs = (u32*)(w + off);  off += (size_t)(NEXP + 1) * T * 4;   // 139 KB
    float* wslot = (float*)(w + off); off += (size_t)T * SLOTS * 4;       //  40 KB
    off = (off + 255) & ~(size_t)255;
    u16*   actb  = (u16*)(w + off);  off += (size_t)T * SLOTS * HID * 2;  // 10.5 MB
    off = (off + 255) & ~(size_t)255;
    u16*   cvtb  = (u16*)(w + off);
    const size_t xChunks = (size_t)T * DIM / 8;
    const size_t cvtChunks = SEG_B5 + xChunks;                            // 3,604,480
    off += cvtChunks * 8 * 2;                                             // 57.7 MB
    off = (off + 255) & ~(size_t)255;
    u16*   eoutb = (u16*)(w + off);
    const size_t needEout = off + (size_t)T * SLOTS * DIM * 2;            // ~89.4 MB

    u16* W1c = cvtb;                       // [17][HID][DIM] (sw1 = expert 16)
    u16* W3c = cvtb + SEG_B1 * 8;
    u16* W2c = cvtb + SEG_B3 * 8;
    u16* xb  = cvtb + SEG_B5 * 8;

    const int useEout = (ws_size >= needEout) ? 1 : 0;   // constant -> graph-safe

    hipMemsetAsync(w, 0, 256, stream);                   // counts
    if (!useEout)
        hipMemsetAsync(out, 0, (size_t)T * DIM * sizeof(float), stream);

    const int nCvt = (int)(cvtChunks / 256);             // chunk count is 256-aligned
    moe_prep<<<nCvt + T, 256, 0, stream>>>(
        x, gate, w1, w3, w2, sw1, sw3, sw2, cvtb, nCvt, counts, pairs, wslot, T);
    moe_build_tiles<<<1, 64, 0, stream>>>(counts, tileE, tileR0, tileNV, tot, T);

    moe_gemm1<<<dim3(HID / 64, MAXT128), 256, 0, stream>>>(
        xb, W1c, W3c, pairs, tileE, tileR0, tileNV, tot, actb, T);
    moe_gemm2<<<dim3(DIM / 128, MAXT128), 256, 0, stream>>>(
        actb, W2c, pairs, wslot, tileE, tileR0, tileNV, tot, eoutb, out, useEout, T);
    if (useEout)
        moe_combine<<<(T * DIM / 4 + 255) / 256, 256, 0, stream>>>(
            eoutb, out, T * DIM / 4);
}